// Round 1
// baseline (274.090 us; speedup 1.0000x reference)
//
#include <hip/hip_runtime.h>

// ---------------------------------------------------------------------------
// ConfidenceBiasedCrossAttention: bf16-MFMA pipeline
//   B=2, Lq=1024, Lk=4096, C=1024, H=16, D=64
//   stages: cvt weights -> Q/K/V projection GEMMs -> flash attn -> O GEMM
// ws layout (48 MB): Wqb(2M) Wkb(2M) Wvb(2M) Wob(2M) qh(4M) kh(16M) vT(16M) ao(4M)
// ---------------------------------------------------------------------------

typedef __attribute__((ext_vector_type(8))) __bf16 bf16x8;
typedef __attribute__((ext_vector_type(4))) float f32x4;

__device__ __forceinline__ unsigned short f2bf(float f) {
  union { float f; unsigned u; } v; v.f = f;
  unsigned r = v.u + 0x7fffu + ((v.u >> 16) & 1u);   // RNE
  return (unsigned short)(r >> 16);
}

__device__ __forceinline__ f32x4 mfma16(bf16x8 a, bf16x8 b, f32x4 c) {
  return __builtin_amdgcn_mfma_f32_16x16x32_bf16(a, b, c, 0, 0, 0);
}

// ------------------------------ weight convert ------------------------------
struct Cvt4 {
  const float* src[4];
  unsigned short* dst[4];
};

__global__ __launch_bounds__(256) void cvt4_kernel(Cvt4 a, int n4) {
  const float4* s = (const float4*)a.src[blockIdx.y];
  unsigned short* d = a.dst[blockIdx.y];
  int stride = gridDim.x * blockDim.x;
  for (int i = blockIdx.x * blockDim.x + threadIdx.x; i < n4; i += stride) {
    float4 f = s[i];
    ushort4 u;
    u.x = f2bf(f.x); u.y = f2bf(f.y); u.z = f2bf(f.z); u.w = f2bf(f.w);
    ((ushort4*)d)[i] = u;
  }
}

// ------------------------------ projection GEMM -----------------------------
// out[m][n] = sum_k A[m][k] * W[n][k] + bias[n]   (torch Linear, W row-major)
// MODE 0: out bf16, head-split  [b][h][l][64]   (Q / K projections)
// MODE 1: out bf16, transposed  vT[b][h][d][Lk]  (V projection; swapped mfma)
// MODE 2: out fp32, plain [M][N]                 (output projection)
// AF32:   A source is fp32 (convert during staging) else bf16.
template <int MODE, bool AF32>
__global__ __launch_bounds__(256) void gemm_bf16(
    const void* __restrict__ Ap, const unsigned short* __restrict__ W,
    const float* __restrict__ bias, void* __restrict__ outp,
    int M, int Llog2) {
  constexpr int K = 1024, N = 1024;
  __shared__ unsigned short Alds[128][40];   // +8 pad: bank spread, 16B align
  __shared__ unsigned short Blds[128][40];

  const int tid = threadIdx.x;
  const int wid = tid >> 6, l = tid & 63;
  const int wr = wid >> 1, wc = wid & 1;
  const int m0 = blockIdx.x * 128, n0 = blockIdx.y * 128;
  const int lg = l >> 4, lm = l & 15;

  const int crow = tid >> 2;          // staging row 0..63 (+64 second chunk)
  const int ck8 = (tid & 3) * 8;      // staging col (8 bf16 per chunk)

  const float* Af = (const float*)Ap;
  const unsigned short* Ab = (const unsigned short*)Ap;

  f32x4 acc[4][4] = {};
  uint4 ra[2], rb[2];

  auto loadA = [&](int kt, int half) -> uint4 {
    const int row = crow + half * 64;
    const long off = (long)(m0 + row) * K + kt * 32 + ck8;
    if constexpr (AF32) {
      float4 f0 = *(const float4*)(Af + off);
      float4 f1 = *(const float4*)(Af + off + 4);
      uint4 u;
      u.x = (unsigned)f2bf(f0.x) | ((unsigned)f2bf(f0.y) << 16);
      u.y = (unsigned)f2bf(f0.z) | ((unsigned)f2bf(f0.w) << 16);
      u.z = (unsigned)f2bf(f1.x) | ((unsigned)f2bf(f1.y) << 16);
      u.w = (unsigned)f2bf(f1.z) | ((unsigned)f2bf(f1.w) << 16);
      return u;
    } else {
      return *(const uint4*)(Ab + off);
    }
  };
  auto loadB = [&](int kt, int half) -> uint4 {
    const int row = crow + half * 64;
    return *(const uint4*)(W + (long)(n0 + row) * K + kt * 32 + ck8);
  };

  ra[0] = loadA(0, 0); ra[1] = loadA(0, 1);
  rb[0] = loadB(0, 0); rb[1] = loadB(0, 1);

  for (int kt = 0; kt < K / 32; ++kt) {
    __syncthreads();                       // prior compute done reading LDS
    *(uint4*)&Alds[crow][ck8] = ra[0];
    *(uint4*)&Alds[crow + 64][ck8] = ra[1];
    *(uint4*)&Blds[crow][ck8] = rb[0];
    *(uint4*)&Blds[crow + 64][ck8] = rb[1];
    __syncthreads();
    if (kt + 1 < K / 32) {                 // prefetch next tile under compute
      ra[0] = loadA(kt + 1, 0); ra[1] = loadA(kt + 1, 1);
      rb[0] = loadB(kt + 1, 0); rb[1] = loadB(kt + 1, 1);
    }
    bf16x8 af[4], bfr[4];
#pragma unroll
    for (int i = 0; i < 4; ++i)
      af[i] = *(const bf16x8*)&Alds[wr * 64 + i * 16 + lm][lg * 8];
#pragma unroll
    for (int j = 0; j < 4; ++j)
      bfr[j] = *(const bf16x8*)&Blds[wc * 64 + j * 16 + lm][lg * 8];
#pragma unroll
    for (int i = 0; i < 4; ++i)
#pragma unroll
      for (int j = 0; j < 4; ++j) {
        if constexpr (MODE == 1)
          acc[i][j] = mfma16(bfr[i], af[j], acc[i][j]);  // D^T = W * A^T
        else
          acc[i][j] = mfma16(af[i], bfr[j], acc[i][j]);
      }
  }

  // epilogue: D layout col = lm, row = lg*4 + r   [m89-verified]
  const int rr = lg * 4;
  if constexpr (MODE == 0) {
    const int Lmask = (1 << Llog2) - 1;
    unsigned short* out = (unsigned short*)outp;
#pragma unroll
    for (int j = 0; j < 4; ++j) {
      const int n = n0 + wc * 64 + j * 16 + lm;
      const float bv = bias[n];
      const int h = n >> 6, d = n & 63;
#pragma unroll
      for (int i = 0; i < 4; ++i)
#pragma unroll
        for (int r = 0; r < 4; ++r) {
          const int m = m0 + wr * 64 + i * 16 + rr + r;
          const int b = m >> Llog2, li = m & Lmask;
          const long o = (((long)(b * 16 + h) << Llog2) + li) * 64 + d;
          out[o] = f2bf(acc[i][j][r] + bv);
        }
    }
  } else if constexpr (MODE == 1) {
    unsigned short* out = (unsigned short*)outp;
#pragma unroll
    for (int i = 0; i < 4; ++i)
#pragma unroll
      for (int r = 0; r < 4; ++r) {
        const int n = n0 + wc * 64 + i * 16 + rr + r;   // D rows = n (weight)
        const float bv = bias[n];
        const int h = n >> 6, d = n & 63;
#pragma unroll
        for (int j = 0; j < 4; ++j) {
          const int m = m0 + wr * 64 + j * 16 + lm;     // D cols = m (lk)
          const int b = m >> 12, lk = m & 4095;
          const long o = ((long)((b * 16 + h) * 64 + d)) * 4096 + lk;
          out[o] = f2bf(acc[i][j][r] + bv);
        }
      }
  } else {  // MODE 2: fp32 [M][N]
    float* out = (float*)outp;
#pragma unroll
    for (int j = 0; j < 4; ++j) {
      const int n = n0 + wc * 64 + j * 16 + lm;
      const float bv = bias[n];
#pragma unroll
      for (int i = 0; i < 4; ++i)
#pragma unroll
        for (int r = 0; r < 4; ++r) {
          const int m = m0 + wr * 64 + i * 16 + rr + r;
          out[(long)m * N + n] = acc[i][j][r] + bv;
        }
    }
  }
}

// ------------------------------ flash attention -----------------------------
// grid: (16 q-blocks, 32 bh); 256 threads = 4 waves, wave owns 16 q rows.
// qh [bh][1024][64], kh [bh][4096][64], vT [bh][64][4096], Vb [b][4096]
// ao [b][lq][h*64+d] bf16
__global__ __launch_bounds__(256) void attn_fwd(
    const unsigned short* __restrict__ qh, const unsigned short* __restrict__ kh,
    const unsigned short* __restrict__ vT, const float* __restrict__ Vb,
    unsigned short* __restrict__ ao) {
  __shared__ unsigned short Klds[64][72];       // [key][d]
  __shared__ unsigned short Vlds[64][72];       // [d][key] (from vT)
  __shared__ unsigned short Plds[4][16][72];    // per-wave P [qrow][key]

  const int tid = threadIdx.x, wid = tid >> 6, l = tid & 63;
  const int qb = blockIdx.x;   // 0..15
  const int bh = blockIdx.y;   // 0..31
  const int b = bh >> 4, h = bh & 15;
  const int q0 = qb * 64;
  const int lg = l >> 4, lm = l & 15;

  // Q fragments held in registers for the whole kernel
  const unsigned short* qp =
      qh + ((long)bh * 1024 + q0 + wid * 16 + lm) * 64 + lg * 8;
  const bf16x8 aq0 = *(const bf16x8*)qp;
  const bf16x8 aq1 = *(const bf16x8*)(qp + 32);

  const unsigned short* kbase = kh + (long)bh * 4096 * 64;
  const unsigned short* vbase = vT + (long)bh * 64 * 4096;

  const int srow = tid >> 3;        // 0..31 (+32 for second chunk)
  const int soff = (tid & 7) * 8;

  float Mr[4], Lr[4];
  f32x4 oacc[4] = {};
#pragma unroll
  for (int r = 0; r < 4; ++r) { Mr[r] = -1e30f; Lr[r] = 0.f; }

  uint4 rk0, rk1, rv0, rv1;
  auto loadKV = [&](int kt) {
    rk0 = *(const uint4*)(kbase + (long)(kt * 64 + srow) * 64 + soff);
    rk1 = *(const uint4*)(kbase + (long)(kt * 64 + srow + 32) * 64 + soff);
    rv0 = *(const uint4*)(vbase + (long)srow * 4096 + kt * 64 + soff);
    rv1 = *(const uint4*)(vbase + (long)(srow + 32) * 4096 + kt * 64 + soff);
  };
  loadKV(0);

  for (int kt = 0; kt < 64; ++kt) {
    __syncthreads();                  // prior PV done with Klds/Vlds
    *(uint4*)&Klds[srow][soff] = rk0;
    *(uint4*)&Klds[srow + 32][soff] = rk1;
    *(uint4*)&Vlds[srow][soff] = rv0;
    *(uint4*)&Vlds[srow + 32][soff] = rv1;
    __syncthreads();
    if (kt + 1 < 64) loadKV(kt + 1);  // prefetch under compute

    // S = q K^T   (16 x 64 per wave)
    f32x4 sacc[4] = {};
#pragma unroll
    for (int nb = 0; nb < 4; ++nb) {
      bf16x8 bk0 = *(const bf16x8*)&Klds[nb * 16 + lm][lg * 8];
      bf16x8 bk1 = *(const bf16x8*)&Klds[nb * 16 + lm][32 + lg * 8];
      sacc[nb] = mfma16(aq0, bk0, sacc[nb]);
      sacc[nb] = mfma16(aq1, bk1, sacc[nb]);
    }
    // scale + per-key bias
    float sv[4][4];
#pragma unroll
    for (int nb = 0; nb < 4; ++nb) {
      const float bvv = Vb[b * 4096 + kt * 64 + nb * 16 + lm];
#pragma unroll
      for (int r = 0; r < 4; ++r) sv[nb][r] = sacc[nb][r] * 0.125f + bvv;
    }
    // online softmax (rows live across the 16-lane group)
    float tmax[4];
#pragma unroll
    for (int r = 0; r < 4; ++r)
      tmax[r] = fmaxf(fmaxf(sv[0][r], sv[1][r]), fmaxf(sv[2][r], sv[3][r]));
#pragma unroll
    for (int mk = 1; mk < 16; mk <<= 1)
#pragma unroll
      for (int r = 0; r < 4; ++r)
        tmax[r] = fmaxf(tmax[r], __shfl_xor(tmax[r], mk));
    float alpha[4], tsum[4];
#pragma unroll
    for (int r = 0; r < 4; ++r) {
      const float mnew = fmaxf(Mr[r], tmax[r]);
      alpha[r] = __expf(Mr[r] - mnew);
      Mr[r] = mnew;
    }
#pragma unroll
    for (int nb = 0; nb < 4; ++nb)
#pragma unroll
      for (int r = 0; r < 4; ++r) sv[nb][r] = __expf(sv[nb][r] - Mr[r]);
#pragma unroll
    for (int r = 0; r < 4; ++r)
      tsum[r] = (sv[0][r] + sv[1][r]) + (sv[2][r] + sv[3][r]);
#pragma unroll
    for (int mk = 1; mk < 16; mk <<= 1)
#pragma unroll
      for (int r = 0; r < 4; ++r) tsum[r] += __shfl_xor(tsum[r], mk);
#pragma unroll
    for (int r = 0; r < 4; ++r) Lr[r] = Lr[r] * alpha[r] + tsum[r];
#pragma unroll
    for (int db = 0; db < 4; ++db)
#pragma unroll
      for (int r = 0; r < 4; ++r) oacc[db][r] *= alpha[r];

    // P -> per-wave LDS (bf16), then PV
#pragma unroll
    for (int nb = 0; nb < 4; ++nb)
#pragma unroll
      for (int r = 0; r < 4; ++r)
        Plds[wid][lg * 4 + r][nb * 16 + lm] = f2bf(sv[nb][r]);
    asm volatile("s_waitcnt lgkmcnt(0)" ::: "memory");

    bf16x8 ap0 = *(const bf16x8*)&Plds[wid][lm][lg * 8];
    bf16x8 ap1 = *(const bf16x8*)&Plds[wid][lm][32 + lg * 8];
#pragma unroll
    for (int db = 0; db < 4; ++db) {
      bf16x8 bv0 = *(const bf16x8*)&Vlds[db * 16 + lm][lg * 8];
      bf16x8 bv1 = *(const bf16x8*)&Vlds[db * 16 + lm][32 + lg * 8];
      oacc[db] = mfma16(ap0, bv0, oacc[db]);
      oacc[db] = mfma16(ap1, bv1, oacc[db]);
    }
  }

  // epilogue: O / L  -> ao[b][lq][h*64+d]
  float inv[4];
#pragma unroll
  for (int r = 0; r < 4; ++r) inv[r] = 1.f / Lr[r];
#pragma unroll
  for (int db = 0; db < 4; ++db)
#pragma unroll
    for (int r = 0; r < 4; ++r) {
      const int row = q0 + wid * 16 + lg * 4 + r;
      const int col = h * 64 + db * 16 + lm;
      ao[((long)b * 1024 + row) * 1024 + col] = f2bf(oacc[db][r] * inv[r]);
    }
}

// --------------------------------- launcher ---------------------------------
extern "C" void kernel_launch(void* const* d_in, const int* in_sizes, int n_in,
                              void* d_out, int out_size, void* d_ws,
                              size_t ws_size, hipStream_t stream) {
  const float* Q = (const float*)d_in[0];
  const float* K_in = (const float*)d_in[1];
  const float* V_in = (const float*)d_in[2];
  const float* V_bias = (const float*)d_in[3];
  const float* Wq_w = (const float*)d_in[4];
  const float* Wq_b = (const float*)d_in[5];
  const float* Wk_w = (const float*)d_in[6];
  const float* Wk_b = (const float*)d_in[7];
  const float* Wv_w = (const float*)d_in[8];
  const float* Wv_b = (const float*)d_in[9];
  const float* Wo_w = (const float*)d_in[10];
  const float* Wo_b = (const float*)d_in[11];

  char* ws = (char*)d_ws;  // needs 48 MB
  unsigned short* Wqb = (unsigned short*)(ws + (0l << 20));
  unsigned short* Wkb = (unsigned short*)(ws + (2l << 20));
  unsigned short* Wvb = (unsigned short*)(ws + (4l << 20));
  unsigned short* Wob = (unsigned short*)(ws + (6l << 20));
  unsigned short* qhp = (unsigned short*)(ws + (8l << 20));   // 4 MB
  unsigned short* khp = (unsigned short*)(ws + (12l << 20));  // 16 MB
  unsigned short* vTp = (unsigned short*)(ws + (28l << 20));  // 16 MB
  unsigned short* aop = (unsigned short*)(ws + (44l << 20));  // 4 MB

  Cvt4 c4;
  c4.src[0] = Wq_w; c4.src[1] = Wk_w; c4.src[2] = Wv_w; c4.src[3] = Wo_w;
  c4.dst[0] = Wqb;  c4.dst[1] = Wkb;  c4.dst[2] = Wvb;  c4.dst[3] = Wob;
  cvt4_kernel<<<dim3(256, 4), 256, 0, stream>>>(c4, (1024 * 1024) / 4);

  gemm_bf16<0, true><<<dim3(16, 8), 256, 0, stream>>>(Q, Wqb, Wq_b, qhp, 2048, 10);
  gemm_bf16<0, true><<<dim3(64, 8), 256, 0, stream>>>(K_in, Wkb, Wk_b, khp, 8192, 12);
  gemm_bf16<1, true><<<dim3(64, 8), 256, 0, stream>>>(V_in, Wvb, Wv_b, vTp, 8192, 12);

  attn_fwd<<<dim3(16, 32), 256, 0, stream>>>(qhp, khp, vTp, V_bias, aop);

  gemm_bf16<2, false><<<dim3(16, 8), 256, 0, stream>>>(aop, Wob, Wo_b, d_out, 2048, 0);
}

// Round 2
// 187.837 us; speedup vs baseline: 1.4592x; 1.4592x over previous
//
#include <hip/hip_runtime.h>

// ---------------------------------------------------------------------------
// ConfidenceBiasedCrossAttention: bf16-MFMA pipeline, round 2
//   B=2, Lq=1024, Lk=4096, C=1024, H=16, D=64
//   stages: cvt weights -> Q/K/V projection GEMMs -> attn (32x32 mfma,
//           swapped QK, in-register P, split-K x2) -> combine -> O GEMM
// ws layout (needs 64.5 MB):
//   0M Wqb | 2M Wkb | 4M Wvb | 6M Wob | 8M qh(4M) | 12M kh(16M) |
//   28M vT(16M) | 44M Opart f32(16M) | 60M ao(4M) | 64M ml(512K)
// ---------------------------------------------------------------------------

typedef __attribute__((ext_vector_type(8))) __bf16 bf16x8;
typedef __attribute__((ext_vector_type(4))) float f32x4;
typedef __attribute__((ext_vector_type(16))) float f32x16;

#define LOG2E 1.44269504f

__device__ __forceinline__ unsigned short f2bf(float f) {
  union { float f; unsigned u; } v; v.f = f;
  unsigned r = v.u + 0x7fffu + ((v.u >> 16) & 1u);   // RNE
  return (unsigned short)(r >> 16);
}

__device__ __forceinline__ f32x4 mfma16(bf16x8 a, bf16x8 b, f32x4 c) {
  return __builtin_amdgcn_mfma_f32_16x16x32_bf16(a, b, c, 0, 0, 0);
}
__device__ __forceinline__ f32x16 mfma32(bf16x8 a, bf16x8 b, f32x16 c) {
  return __builtin_amdgcn_mfma_f32_32x32x16_bf16(a, b, c, 0, 0, 0);
}

// pack two f32 -> u32 of 2 bf16 (compiler emits v_cvt_pk_bf16_f32)
__device__ __forceinline__ unsigned pk2(float lo, float hi) {
  unsigned short a = __builtin_bit_cast(unsigned short, (__bf16)lo);
  unsigned short b = __builtin_bit_cast(unsigned short, (__bf16)hi);
  return (unsigned)a | ((unsigned)b << 16);
}

// ------------------------------ weight convert ------------------------------
struct Cvt4 {
  const float* src[4];
  unsigned short* dst[4];
};

__global__ __launch_bounds__(256) void cvt4_kernel(Cvt4 a, int n4) {
  const float4* s = (const float4*)a.src[blockIdx.y];
  unsigned short* d = a.dst[blockIdx.y];
  int stride = gridDim.x * blockDim.x;
  for (int i = blockIdx.x * blockDim.x + threadIdx.x; i < n4; i += stride) {
    float4 f = s[i];
    ushort4 u;
    u.x = f2bf(f.x); u.y = f2bf(f.y); u.z = f2bf(f.z); u.w = f2bf(f.w);
    ((ushort4*)d)[i] = u;
  }
}

// ------------------------------ projection GEMM -----------------------------
// out[m][n] = (sum_k A[m][k] * W[n][k] + bias[n]) * oscale
// MODE 0: out bf16, head-split  [b][h][l][64]   (Q / K projections)
// MODE 1: out bf16, transposed  vT[b][h][d][Lk]  (V projection; swapped mfma)
// MODE 2: out fp32, plain [M][N]                 (output projection)
template <int MODE, bool AF32>
__global__ __launch_bounds__(256) void gemm_bf16(
    const void* __restrict__ Ap, const unsigned short* __restrict__ W,
    const float* __restrict__ bias, void* __restrict__ outp,
    int M, int Llog2, float oscale) {
  constexpr int K = 1024, N = 1024;
  __shared__ unsigned short Alds[128][40];   // +8 pad
  __shared__ unsigned short Blds[128][40];

  const int tid = threadIdx.x;
  const int wid = tid >> 6, l = tid & 63;
  const int wr = wid >> 1, wc = wid & 1;
  const int m0 = blockIdx.x * 128, n0 = blockIdx.y * 128;
  const int lg = l >> 4, lm = l & 15;

  const int crow = tid >> 2;
  const int ck8 = (tid & 3) * 8;

  const float* Af = (const float*)Ap;
  const unsigned short* Ab = (const unsigned short*)Ap;

  f32x4 acc[4][4] = {};
  uint4 ra[2], rb[2];

  auto loadA = [&](int kt, int half) -> uint4 {
    const int row = crow + half * 64;
    const long off = (long)(m0 + row) * K + kt * 32 + ck8;
    if constexpr (AF32) {
      float4 f0 = *(const float4*)(Af + off);
      float4 f1 = *(const float4*)(Af + off + 4);
      bf16x8 v;
      v[0] = (__bf16)f0.x; v[1] = (__bf16)f0.y;
      v[2] = (__bf16)f0.z; v[3] = (__bf16)f0.w;
      v[4] = (__bf16)f1.x; v[5] = (__bf16)f1.y;
      v[6] = (__bf16)f1.z; v[7] = (__bf16)f1.w;
      uint4 u;
      __builtin_memcpy(&u, &v, 16);
      return u;
    } else {
      return *(const uint4*)(Ab + off);
    }
  };
  auto loadB = [&](int kt, int half) -> uint4 {
    const int row = crow + half * 64;
    return *(const uint4*)(W + (long)(n0 + row) * K + kt * 32 + ck8);
  };

  ra[0] = loadA(0, 0); ra[1] = loadA(0, 1);
  rb[0] = loadB(0, 0); rb[1] = loadB(0, 1);

  for (int kt = 0; kt < K / 32; ++kt) {
    __syncthreads();
    *(uint4*)&Alds[crow][ck8] = ra[0];
    *(uint4*)&Alds[crow + 64][ck8] = ra[1];
    *(uint4*)&Blds[crow][ck8] = rb[0];
    *(uint4*)&Blds[crow + 64][ck8] = rb[1];
    __syncthreads();
    if (kt + 1 < K / 32) {
      ra[0] = loadA(kt + 1, 0); ra[1] = loadA(kt + 1, 1);
      rb[0] = loadB(kt + 1, 0); rb[1] = loadB(kt + 1, 1);
    }
    bf16x8 af[4], bfr[4];
#pragma unroll
    for (int i = 0; i < 4; ++i)
      af[i] = *(const bf16x8*)&Alds[wr * 64 + i * 16 + lm][lg * 8];
#pragma unroll
    for (int j = 0; j < 4; ++j)
      bfr[j] = *(const bf16x8*)&Blds[wc * 64 + j * 16 + lm][lg * 8];
#pragma unroll
    for (int i = 0; i < 4; ++i)
#pragma unroll
      for (int j = 0; j < 4; ++j) {
        if constexpr (MODE == 1)
          acc[i][j] = mfma16(bfr[i], af[j], acc[i][j]);  // D^T = W * A^T
        else
          acc[i][j] = mfma16(af[i], bfr[j], acc[i][j]);
      }
  }

  const int rr = lg * 4;
  if constexpr (MODE == 0) {
    const int Lmask = (1 << Llog2) - 1;
    unsigned short* out = (unsigned short*)outp;
#pragma unroll
    for (int j = 0; j < 4; ++j) {
      const int n = n0 + wc * 64 + j * 16 + lm;
      const float bv = bias[n];
      const int h = n >> 6, d = n & 63;
#pragma unroll
      for (int i = 0; i < 4; ++i)
#pragma unroll
        for (int r = 0; r < 4; ++r) {
          const int m = m0 + wr * 64 + i * 16 + rr + r;
          const int b = m >> Llog2, li = m & Lmask;
          const long o = (((long)(b * 16 + h) << Llog2) + li) * 64 + d;
          out[o] = f2bf((acc[i][j][r] + bv) * oscale);
        }
    }
  } else if constexpr (MODE == 1) {
    unsigned short* out = (unsigned short*)outp;
#pragma unroll
    for (int i = 0; i < 4; ++i)
#pragma unroll
      for (int r = 0; r < 4; ++r) {
        const int n = n0 + wc * 64 + i * 16 + rr + r;
        const float bv = bias[n];
        const int h = n >> 6, d = n & 63;
#pragma unroll
        for (int j = 0; j < 4; ++j) {
          const int m = m0 + wr * 64 + j * 16 + lm;
          const int b = m >> 12, lk = m & 4095;
          const long o = ((long)((b * 16 + h) * 64 + d)) * 4096 + lk;
          out[o] = f2bf(acc[i][j][r] + bv);
        }
      }
  } else {
    float* out = (float*)outp;
#pragma unroll
    for (int j = 0; j < 4; ++j) {
      const int n = n0 + wc * 64 + j * 16 + lm;
      const float bv = bias[n];
#pragma unroll
      for (int i = 0; i < 4; ++i)
#pragma unroll
        for (int r = 0; r < 4; ++r) {
          const int m = m0 + wr * 64 + i * 16 + rr + r;
          out[(long)m * N + n] = acc[i][j][r] + bv;
        }
    }
  }
}

// ------------------------------ flash attention -----------------------------
// grid: (bh=32, qb=8, sp=2); 256 threads = 4 waves, wave owns 32 q rows.
// 32x32x16 mfma, swapped QK (S^T: lane owns one q-row), key-permuted K rows
// so P stays in registers in exact PV B-fragment layout. Split-K x2.
// qh [bh][1024][64] (pre-scaled by 0.125*log2e), kh [bh][4096][64],
// vT [bh][64][4096], Vb [b][4096] (raw f32)
// Opart [sp][bh][1024][64] f32 (unnormalized), ml [sp][bh][1024][2] f32
__global__ __launch_bounds__(256, 2) void attn32(
    const unsigned short* __restrict__ qh, const unsigned short* __restrict__ kh,
    const unsigned short* __restrict__ vT, const float* __restrict__ Vb,
    float* __restrict__ Opart, float* __restrict__ ml) {
  __shared__ unsigned short Klds[2][64][64];
  __shared__ unsigned short Vlds[2][64][64];

  const int tid = threadIdx.x;
  const int wid = tid >> 6, lane = tid & 63;
  const int lq = lane & 31;          // q index (mfma n / C col)
  const int hi = lane >> 5;          // lane half
  const int bh = blockIdx.x;         // 0..31  (xcd = bh%8 -> K/V L2 locality)
  const int qb = blockIdx.y;         // 0..7
  const int sp = blockIdx.z;         // 0..1 (split-K)
  const int b = bh >> 4;
  const int q = qb * 128 + wid * 32 + lq;
  const int kt0 = sp * 32;           // 32 K-tiles of 64 keys each

  // Q fragments (B-operand: lane lq = q, k(d) = hi*8 + j within 16-d window)
  bf16x8 qr[4];
  {
    const unsigned short* qp = qh + ((long)bh * 1024 + q) * 64 + hi * 8;
#pragma unroll
    for (int dc = 0; dc < 4; ++dc) qr[dc] = *(const bf16x8*)(qp + dc * 16);
  }

  // staging: thread -> (row, two 16B slots); global side pre-swizzled
  const int srow = tid >> 2;                 // 0..63
  const int ss0 = (tid & 3) * 2, ss1 = ss0 + 1;
  const int sswz = srow & 7;
  // K LDS row r holds key swap23(r) (bits 2<->3): makes S-accumulator layout
  // equal the PV B-fragment layout (P never leaves registers).
  const int kgrow = (srow & 0x33) | ((srow & 4) << 1) | ((srow & 8) >> 1);
  const unsigned short* kgp =
      kh + ((long)bh * 4096 + kt0 * 64 + kgrow) * 64;
  const unsigned short* vgp =
      vT + ((long)bh * 64 + srow) * 4096 + kt0 * 64;
  const int ko0 = (ss0 ^ sswz) * 8, ko1 = (ss1 ^ sswz) * 8;
  const float* bp = Vb + b * 4096 + kt0 * 64 + hi * 8;

  uint4 kr0, kr1, vr0, vr1;
  auto loadKV = [&](int t) {
    kr0 = *(const uint4*)(kgp + (long)t * 4096 + ko0);
    kr1 = *(const uint4*)(kgp + (long)t * 4096 + ko1);
    vr0 = *(const uint4*)(vgp + t * 64 + ko0);
    vr1 = *(const uint4*)(vgp + t * 64 + ko1);
  };
  loadKV(0);

  const int rsw = lq & 7;                    // read-side swizzle
  float mreg = -1e30f, lreg = 0.f;
  f32x16 oa0 = {}, oa1 = {};

  for (int t = 0; t < 32; ++t) {
    const int buf = t & 1;
    *(uint4*)&Klds[buf][srow][ss0 * 8] = kr0;
    *(uint4*)&Klds[buf][srow][ss1 * 8] = kr1;
    *(uint4*)&Vlds[buf][srow][ss0 * 8] = vr0;
    *(uint4*)&Vlds[buf][srow][ss1 * 8] = vr1;
    if (t + 1 < 32) loadKV(t + 1);           // prefetch under compute

    // bias (scaled to exp2 domain later); bvv[i] aligns with p[i]
    float bvv[32];
#pragma unroll
    for (int kb = 0; kb < 2; ++kb)
#pragma unroll
      for (int g = 0; g < 4; ++g) {
        float4 t4 = *(const float4*)(bp + t * 64 + kb * 32 + (g & 1) * 4 +
                                     (g >> 1) * 16);
        const int o = kb * 16 + g * 4;
        bvv[o] = t4.x; bvv[o + 1] = t4.y; bvv[o + 2] = t4.z; bvv[o + 3] = t4.w;
      }

    __syncthreads();                         // staged tile visible

    // S^T = K' Q  (m = permuted key, n = q)
    f32x16 sa0 = {}, sa1 = {};
#pragma unroll
    for (int dc = 0; dc < 4; ++dc) {
      const int w16 = dc * 2 + hi;
      bf16x8 kf0 = *(const bf16x8*)&Klds[buf][lq][(w16 ^ rsw) * 8];
      bf16x8 kf1 = *(const bf16x8*)&Klds[buf][32 + lq][(w16 ^ rsw) * 8];
      sa0 = mfma32(kf0, qr[dc], sa0);
      sa1 = mfma32(kf1, qr[dc], sa1);
    }

    // p[i]: key (within tile) = (i&7) + 8*hi + 2*(i&8) + 32*(i>>4)
    float p[32];
#pragma unroll
    for (int r = 0; r < 16; ++r) p[r] = fmaf(bvv[r], LOG2E, sa0[r]);
#pragma unroll
    for (int r = 0; r < 16; ++r) p[16 + r] = fmaf(bvv[16 + r], LOG2E, sa1[r]);

    // online softmax (lane owns one q-row; partner lane^32 has other 32 keys)
    float t16[16];
#pragma unroll
    for (int i = 0; i < 16; ++i) t16[i] = fmaxf(p[i], p[i + 16]);
#pragma unroll
    for (int s = 8; s > 0; s >>= 1)
#pragma unroll
      for (int i = 0; i < 8; ++i)
        if (i < s) t16[i] = fmaxf(t16[i], t16[i + s]);
    float mx = fmaxf(t16[0], __shfl_xor(t16[0], 32));
    const float mnew = fmaxf(mreg, mx);
    const float al = __builtin_amdgcn_exp2f(mreg - mnew);
    mreg = mnew;
#pragma unroll
    for (int i = 0; i < 32; ++i) p[i] = __builtin_amdgcn_exp2f(p[i] - mreg);
    float s16[16];
#pragma unroll
    for (int i = 0; i < 16; ++i) s16[i] = p[i] + p[i + 16];
#pragma unroll
    for (int s = 8; s > 0; s >>= 1)
#pragma unroll
      for (int i = 0; i < 8; ++i)
        if (i < s) s16[i] += s16[i + s];
    float sm = s16[0] + __shfl_xor(s16[0], 32);
    lreg = lreg * al + sm;
#pragma unroll
    for (int r = 0; r < 16; ++r) { oa0[r] *= al; oa1[r] *= al; }

    // PV: P already in B-fragment layout (thanks to key permutation)
#pragma unroll
    for (int kc = 0; kc < 4; ++kc) {
      union { uint4 u; bf16x8 v; } pu;
      pu.u = make_uint4(pk2(p[kc * 8 + 0], p[kc * 8 + 1]),
                        pk2(p[kc * 8 + 2], p[kc * 8 + 3]),
                        pk2(p[kc * 8 + 4], p[kc * 8 + 5]),
                        pk2(p[kc * 8 + 6], p[kc * 8 + 7]));
      const int w16 = kc * 2 + hi;
      bf16x8 vf0 = *(const bf16x8*)&Vlds[buf][lq][(w16 ^ rsw) * 8];
      bf16x8 vf1 = *(const bf16x8*)&Vlds[buf][32 + lq][(w16 ^ rsw) * 8];
      oa0 = mfma32(vf0, pu.v, oa0);
      oa1 = mfma32(vf1, pu.v, oa1);
    }
    __syncthreads();                         // all waves done with buf
  }

  // epilogue: unnormalized O partial (f32) + (m, l)
  float* ob = Opart + (((long)sp * 32 + bh) * 1024 + q) * 64;
#pragma unroll
  for (int g = 0; g < 4; ++g) {
    *(float4*)(ob + g * 8 + hi * 4) =
        make_float4(oa0[g * 4], oa0[g * 4 + 1], oa0[g * 4 + 2], oa0[g * 4 + 3]);
    *(float4*)(ob + 32 + g * 8 + hi * 4) =
        make_float4(oa1[g * 4], oa1[g * 4 + 1], oa1[g * 4 + 2], oa1[g * 4 + 3]);
  }
  if (hi == 0)
    *(float2*)(ml + ((long)sp * 32 + bh) * 2048 + q * 2) =
        make_float2(mreg, lreg);
}

// ------------------------------ split-K combine -----------------------------
__global__ __launch_bounds__(256) void combine_kernel(
    const float* __restrict__ Opart, const float* __restrict__ ml,
    unsigned short* __restrict__ ao) {
  const int idx = blockIdx.x * 256 + threadIdx.x;   // 0..32767 (bh*1024+q)
  const int bh = idx >> 10, q = idx & 1023;
  const int b = bh >> 4, h = bh & 15;
  const float2 a0 = *(const float2*)(ml + (long)idx * 2);
  const float2 a1 = *(const float2*)(ml + ((long)32768 + idx) * 2);
  const float mm = fmaxf(a0.x, a1.x);
  const float e0 = __builtin_amdgcn_exp2f(a0.x - mm);
  const float e1 = __builtin_amdgcn_exp2f(a1.x - mm);
  const float inv = 1.0f / (a0.y * e0 + a1.y * e1);
  const float s0 = e0 * inv, s1 = e1 * inv;
  const float* O0 = Opart + (long)idx * 64;
  const float* O1 = Opart + ((long)32768 + idx) * 64;
  unsigned short* op = ao + ((long)b * 1024 + q) * 1024 + h * 64;
#pragma unroll
  for (int d = 0; d < 64; d += 4) {
    float4 x = *(const float4*)(O0 + d);
    float4 y = *(const float4*)(O1 + d);
    ushort4 u;
    u.x = f2bf(x.x * s0 + y.x * s1);
    u.y = f2bf(x.y * s0 + y.y * s1);
    u.z = f2bf(x.z * s0 + y.z * s1);
    u.w = f2bf(x.w * s0 + y.w * s1);
    *(ushort4*)(op + d) = u;
  }
}

// --------------------------------- launcher ---------------------------------
extern "C" void kernel_launch(void* const* d_in, const int* in_sizes, int n_in,
                              void* d_out, int out_size, void* d_ws,
                              size_t ws_size, hipStream_t stream) {
  const float* Q = (const float*)d_in[0];
  const float* K_in = (const float*)d_in[1];
  const float* V_in = (const float*)d_in[2];
  const float* V_bias = (const float*)d_in[3];
  const float* Wq_w = (const float*)d_in[4];
  const float* Wq_b = (const float*)d_in[5];
  const float* Wk_w = (const float*)d_in[6];
  const float* Wk_b = (const float*)d_in[7];
  const float* Wv_w = (const float*)d_in[8];
  const float* Wv_b = (const float*)d_in[9];
  const float* Wo_w = (const float*)d_in[10];
  const float* Wo_b = (const float*)d_in[11];

  char* ws = (char*)d_ws;  // needs 64.5 MB
  unsigned short* Wqb = (unsigned short*)(ws + (0l << 20));
  unsigned short* Wkb = (unsigned short*)(ws + (2l << 20));
  unsigned short* Wvb = (unsigned short*)(ws + (4l << 20));
  unsigned short* Wob = (unsigned short*)(ws + (6l << 20));
  unsigned short* qhp = (unsigned short*)(ws + (8l << 20));   // 4 MB
  unsigned short* khp = (unsigned short*)(ws + (12l << 20));  // 16 MB
  unsigned short* vTp = (unsigned short*)(ws + (28l << 20));  // 16 MB
  float* Opart = (float*)(ws + (44l << 20));                  // 16 MB
  unsigned short* aop = (unsigned short*)(ws + (60l << 20));  // 4 MB
  float* mlp = (float*)(ws + (64l << 20));                    // 512 KB

  Cvt4 c4;
  c4.src[0] = Wq_w; c4.src[1] = Wk_w; c4.src[2] = Wv_w; c4.src[3] = Wo_w;
  c4.dst[0] = Wqb;  c4.dst[1] = Wkb;  c4.dst[2] = Wvb;  c4.dst[3] = Wob;
  cvt4_kernel<<<dim3(256, 4), 256, 0, stream>>>(c4, (1024 * 1024) / 4);

  // Q pre-scaled by 1/sqrt(D) * log2(e) so attention works in exp2 domain
  gemm_bf16<0, true><<<dim3(16, 8), 256, 0, stream>>>(
      Q, Wqb, Wq_b, qhp, 2048, 10, 0.125f * LOG2E);
  gemm_bf16<0, true><<<dim3(64, 8), 256, 0, stream>>>(
      K_in, Wkb, Wk_b, khp, 8192, 12, 1.0f);
  gemm_bf16<1, true><<<dim3(64, 8), 256, 0, stream>>>(
      V_in, Wvb, Wv_b, vTp, 8192, 12, 1.0f);

  attn32<<<dim3(32, 8, 2), 256, 0, stream>>>(qhp, khp, vTp, V_bias, Opart, mlp);
  combine_kernel<<<128, 256, 0, stream>>>(Opart, mlp, aop);

  gemm_bf16<2, false><<<dim3(16, 8), 256, 0, stream>>>(
      aop, Wob, Wo_b, d_out, 2048, 0, 1.0f);
}